// Round 19
// baseline (851.407 us; speedup 1.0000x reference)
//
#include <hip/hip_runtime.h>
#include <hip/hip_bf16.h>

typedef unsigned short u16;
typedef __attribute__((ext_vector_type(4))) float f32x4;
typedef __attribute__((ext_vector_type(8))) short bf16x8;
typedef __attribute__((ext_vector_type(8))) unsigned short u16x8;
typedef __attribute__((ext_vector_type(4))) unsigned short u16x4;

__device__ __forceinline__ u16 f2bf(float f) {
  union { float f; unsigned u; } v; v.f = f;
  unsigned r = v.u + 0x7FFFu + ((v.u >> 16) & 1u);
  return (u16)(r >> 16);
}
__device__ __forceinline__ float bf2f(u16 v) {
  union { float f; unsigned u; } x; x.u = (unsigned)v << 16; return x.f;
}

__device__ __forceinline__ int xswz(int wg, int n) {  // bijective XCD swizzle, n%8==0
  return (wg & 7) * (n >> 3) + (wg >> 3);
}

// =================================================================== 8-phase 256^2 GEMM core
__device__ __forceinline__ void g8_stage_half(
    const u16* __restrict__ G, int ldg, int tile, int half, u16* ldsbase) {
  const int tid = threadIdx.x;
#pragma unroll
  for (int load = 0; load < 2; ++load) {
    int unit = load * 512 + tid;
    int row = unit >> 3;
    int seg = (unit & 7) ^ ((unit >> 3) & 7);  // pre-swizzled source segment
    __builtin_amdgcn_global_load_lds(
        (const __attribute__((address_space(1))) void*)(G + (size_t)(half * 128 + row) * ldg + tile * 64 + seg * 8),
        (__attribute__((address_space(3))) void*)(ldsbase + half * 8192 + load * 4096 + (tid >> 6) * 512),
        16, 0, 0);
  }
}

__device__ __forceinline__ void g8_core(
    const u16* __restrict__ A, int lda, const u16* __restrict__ Bt, int ldb,
    int NT, u16* lds, f32x4 acc[8][4]) {
  const int tid = threadIdx.x;
  const int lane = tid & 63;
  const int wid = tid >> 6;
  const int wr = wid >> 2, wc = wid & 3;
  const int lr = lane & 15;
  const int lk4 = lane >> 4;
  const int sw = lane & 7;
  const int off0 = ((lk4 ^ sw) * 8);
  const int off1 = (((4 + lk4) ^ sw) * 8);

  u16* ldsA = lds;           // [buf][half][128][64]
  u16* ldsB = lds + 32768;

  g8_stage_half(A, lda, 0, 0, ldsA);
  g8_stage_half(A, lda, 0, 1, ldsA);
  g8_stage_half(Bt, ldb, 0, 0, ldsB);
  g8_stage_half(Bt, ldb, 0, 1, ldsB);
  if (NT > 1) {
    g8_stage_half(Bt, ldb, 1, 0, ldsB + 16384);
    g8_stage_half(Bt, ldb, 1, 1, ldsB + 16384);
  }
  asm volatile("s_waitcnt vmcnt(4)" ::: "memory");
  __builtin_amdgcn_s_barrier();
  __builtin_amdgcn_sched_barrier(0);

  for (int g = 0; g < NT; ++g) {
    const int buf = g & 1;
    const u16* cA = ldsA + buf * 16384 + wr * 8192;
    const u16* cB = ldsB + buf * 16384;
    bf16x8 bv[4][2];
#pragma unroll
    for (int p = 0; p < 4; ++p) {
      bf16x8 av[2][2];
      if (p == 0) {
#pragma unroll
        for (int n = 0; n < 4; ++n) {
          int rg = wc * 64 + n * 16 + lr;
          const u16* rbase = &cB[(rg >> 7) * 8192 + (rg & 127) * 64];
          bv[n][0] = *(const bf16x8*)&rbase[off0];
          bv[n][1] = *(const bf16x8*)&rbase[off1];
        }
      }
#pragma unroll
      for (int m2 = 0; m2 < 2; ++m2) {
        const u16* rbase = &cA[((p * 2 + m2) * 16 + lr) * 64];
        av[m2][0] = *(const bf16x8*)&rbase[off0];
        av[m2][1] = *(const bf16x8*)&rbase[off1];
      }

      if (p == 0 && g + 1 < NT) g8_stage_half(A, lda, g + 1, 0, ldsA + ((g + 1) & 1) * 16384);
      if (p == 1 && g + 1 < NT) g8_stage_half(A, lda, g + 1, 1, ldsA + ((g + 1) & 1) * 16384);
      if (p == 2 && g + 2 < NT) g8_stage_half(Bt, ldb, g + 2, 0, ldsB + buf * 16384);
      if (p == 3) {
        if (g + 2 < NT) {
          g8_stage_half(Bt, ldb, g + 2, 1, ldsB + buf * 16384);
          asm volatile("s_waitcnt vmcnt(4)" ::: "memory");
        } else if (g + 1 < NT) {
          asm volatile("s_waitcnt vmcnt(0)" ::: "memory");
        }
      }
      __builtin_amdgcn_s_barrier();
      asm volatile("s_waitcnt lgkmcnt(0)" ::: "memory");
      __builtin_amdgcn_sched_barrier(0);
      __builtin_amdgcn_s_setprio(1);
#pragma unroll
      for (int m2 = 0; m2 < 2; ++m2)
#pragma unroll
        for (int n = 0; n < 4; ++n)
#pragma unroll
          for (int kk = 0; kk < 2; ++kk)
            acc[p * 2 + m2][n] = __builtin_amdgcn_mfma_f32_16x16x32_bf16(
                av[m2][kk], bv[n][kk], acc[p * 2 + m2][n], 0, 0, 0);
      __builtin_amdgcn_s_setprio(0);
      __builtin_amdgcn_sched_barrier(0);
      __builtin_amdgcn_s_barrier();
    }
  }
}

__device__ __forceinline__ void g8_acc_zero(f32x4 acc[8][4]) {
#pragma unroll
  for (int m = 0; m < 8; ++m)
#pragma unroll
    for (int n = 0; n < 4; ++n)
      acc[m][n] = (f32x4){0.f, 0.f, 0.f, 0.f};
}

__device__ __forceinline__ void acc_zero4(f32x4 acc[4][4]) {
#pragma unroll
  for (int m = 0; m < 4; ++m)
#pragma unroll
    for (int n = 0; n < 4; ++n)
      acc[m][n] = (f32x4){0.f, 0.f, 0.f, 0.f};
}

// ------------------------------------------------------------------- csf512
// 512-thread compacted f32-W audio GEMM (128x128 tile) for merged dispatches.
__device__ __forceinline__ void csf512_body(
    const u16* __restrict__ Ab, int lda, const float* __restrict__ Wb, int ldw,
    int ksteps, int amax, u16* lds, u16* __restrict__ Pout, int ldc) {
  u16* sA = lds;
  u16* sB = lds + 16384;
  const int tid = threadIdx.x;
  const int wave = tid >> 6, lane = tid & 63;
  const int lr = lane & 15, lk4 = lane >> 4, sw = lane & 7;
  const int off0 = ((lk4 ^ sw) * 8), off1 = (((4 + lk4) ^ sw) * 8);
  const int srow = tid >> 3;
  const int ssw = (tid & 7) ^ ((tid >> 3) & 7);
  const int kb = tid >> 5;
  const int bn4 = (tid & 31) * 4;
  f32x4 breg[4];

  auto stageA = [&](int buf, int kt) {
    const int kk0 = kt * 64;
#pragma unroll
    for (int i = 0; i < 2; ++i) {
      int ra = i * 64 + srow; if (ra > amax) ra = amax;
      __builtin_amdgcn_global_load_lds(
          (const __attribute__((address_space(1))) void*)(Ab + (size_t)ra * lda + kk0 + ssw * 8),
          (__attribute__((address_space(3))) void*)(sA + buf * 8192 + i * 4096 + wave * 512),
          16, 0, 0);
    }
  };
  auto loadB = [&](int kt) {
#pragma unroll
    for (int i = 0; i < 4; ++i) {
      int kk = kt * 64 + i * 16 + kb;
      breg[i] = __builtin_nontemporal_load((const f32x4*)&Wb[(size_t)kk * ldw + bn4]);
    }
  };
  auto writeB = [&](int buf) {
    u16* dB = sB + buf * 8192;
#pragma unroll
    for (int i = 0; i < 4; ++i) {
      int kk = i * 16 + kb;
#pragma unroll
      for (int j = 0; j < 4; ++j) {
        int n = bn4 + j;
        dB[n * 64 + (((kk >> 3) ^ (n & 7)) * 8) + (kk & 7)] = f2bf(breg[i][j]);
      }
    }
  };

  f32x4 acc[4][4];
  acc_zero4(acc);

  stageA(0, 0);
  loadB(0);
  asm volatile("s_waitcnt vmcnt(0)" ::: "memory");
  writeB(0);
  asm volatile("s_waitcnt lgkmcnt(0)" ::: "memory");
  __builtin_amdgcn_s_barrier();
  __builtin_amdgcn_sched_barrier(0);

  const int wm = (wave >> 1) * 64, wn = (wave & 1) * 64;
  for (int kt = 0; kt < ksteps; ++kt) {
    const int cur = kt & 1;
    if (kt + 1 < ksteps) { stageA(cur ^ 1, kt + 1); loadB(kt + 1); }
    if (wave < 4) {
      const u16* cA = sA + cur * 8192;
      const u16* cB = sB + cur * 8192;
#pragma unroll
      for (int kk = 0; kk < 2; ++kk) {
        const int off = kk ? off1 : off0;
        bf16x8 av[4], bv[4];
#pragma unroll
        for (int m = 0; m < 4; ++m)
          av[m] = *(const bf16x8*)&cA[(wm + m * 16 + lr) * 64 + off];
#pragma unroll
        for (int n = 0; n < 4; ++n)
          bv[n] = *(const bf16x8*)&cB[(wn + n * 16 + lr) * 64 + off];
#pragma unroll
        for (int m = 0; m < 4; ++m)
#pragma unroll
          for (int n = 0; n < 4; ++n)
            acc[m][n] = __builtin_amdgcn_mfma_f32_16x16x32_bf16(av[m], bv[n], acc[m][n], 0, 0, 0);
      }
    }
    asm volatile("s_waitcnt vmcnt(0)" ::: "memory");
    if (kt + 1 < ksteps) writeB(cur ^ 1);
    asm volatile("s_waitcnt lgkmcnt(0)" ::: "memory");
    __builtin_amdgcn_s_barrier();
    __builtin_amdgcn_sched_barrier(0);
  }
  if (wave < 4) {
    const int col = lane & 15, rb = (lane >> 4) * 4;
#pragma unroll
    for (int m = 0; m < 4; ++m)
#pragma unroll
      for (int n = 0; n < 4; ++n)
#pragma unroll
        for (int j = 0; j < 4; ++j)
          Pout[(size_t)(wm + m * 16 + rb + j) * ldc + wn + n * 16 + col] = f2bf(acc[m][n][j]);
  }
}

// qkv split-K x2 -> bf16 partials [2][2048][4096]
__global__ __launch_bounds__(512, 2) void k_gemm8_qkv(
    const u16* __restrict__ A, const u16* __restrict__ Bt, u16* __restrict__ Pq) {
  __shared__ u16 lds[65536];
  const int wg = xswz(blockIdx.x, 256);
  const int ks = wg >> 7, rem = wg & 127;
  const int tm = rem >> 4, tn = rem & 15;
  f32x4 acc[8][4];
  g8_acc_zero(acc);
  g8_core(A + (size_t)tm * 256 * 2048 + ks * 1024, 2048,
          Bt + (size_t)tn * 256 * 2048 + ks * 1024, 2048, 16, lds, acc);
  const int lane = threadIdx.x & 63, wid = threadIdx.x >> 6;
  const int wr = wid >> 2, wc = wid & 3;
  const int col = lane & 15, rb = (lane >> 4) * 4;
#pragma unroll
  for (int m = 0; m < 8; ++m)
#pragma unroll
    for (int n = 0; n < 4; ++n)
#pragma unroll
      for (int j = 0; j < 4; ++j) {
        int gm = tm * 256 + wr * 128 + m * 16 + rb + j;
        int gn = tn * 256 + wc * 64 + n * 16 + col;
        Pq[((size_t)ks * 2048 + gm) * 4096 + gn] = f2bf(acc[m][n][j]);
      }
}

// o-proj split-K x4 -> bf16 partials [4][2048][2048]
__global__ __launch_bounds__(512, 2) void k_gemm8_sk(
    const u16* __restrict__ A, int lda, const u16* __restrict__ Bt, int ldb,
    int NT, int koff, u16* __restrict__ Pp) {
  __shared__ u16 lds[65536];
  const int wg = xswz(blockIdx.x, 256);
  const int ks = wg >> 6, rem = wg & 63;
  const int tm = rem >> 3, tn = rem & 7;
  f32x4 acc[8][4];
  g8_acc_zero(acc);
  g8_core(A + (size_t)tm * 256 * lda + ks * koff, lda,
          Bt + (size_t)tn * 256 * ldb + ks * koff, ldb, NT, lds, acc);
  const int lane = threadIdx.x & 63, wid = threadIdx.x >> 6;
  const int wr = wid >> 2, wc = wid & 3;
  const int col = lane & 15, rb = (lane >> 4) * 4;
#pragma unroll
  for (int m = 0; m < 8; ++m)
#pragma unroll
    for (int n = 0; n < 4; ++n)
#pragma unroll
      for (int j = 0; j < 4; ++j) {
        int gm = tm * 256 + wr * 128 + m * 16 + rb + j;
        int gn = tn * 256 + wc * 64 + n * 16 + col;
        Pp[((size_t)ks * 2048 + gm) * 2048 + gn] = f2bf(acc[m][n][j]);
      }
}

// MERGED: text fc (blocks 0..255) + audio fc (blocks 256..767, csf512, split-K x4)
__global__ __launch_bounds__(512, 2) void k_fc_afc(
    const u16* __restrict__ A, const u16* __restrict__ Bt, u16* __restrict__ Cb,
    const u16* __restrict__ xc, const float* __restrict__ w_afc,
    u16* __restrict__ Pafc, const int* __restrict__ cnt) {
  __shared__ u16 lds[65536];
  if (blockIdx.x < 256) {
    const int wg = xswz(blockIdx.x, 256);
    const int tm = wg >> 5, tn = wg & 31;
    f32x4 acc[8][4];
    g8_acc_zero(acc);
    g8_core(A + (size_t)tm * 256 * 2048, 2048, Bt + (size_t)tn * 256 * 2048, 2048, 32, lds, acc);
    const int lane = threadIdx.x & 63, wid = threadIdx.x >> 6;
    const int wr = wid >> 2, wc = wid & 3;
    const int col = lane & 15, rb = (lane >> 4) * 4;
#pragma unroll
    for (int m = 0; m < 8; ++m)
#pragma unroll
      for (int n = 0; n < 4; ++n)
#pragma unroll
        for (int j = 0; j < 4; ++j) {
          int gm = tm * 256 + wr * 128 + m * 16 + rb + j;
          int gn = tn * 256 + wc * 64 + n * 16 + col;
          float v = acc[m][n][j];
          Cb[(size_t)gm * 8192 + gn] = f2bf(v / (1.f + __expf(-v)));
        }
  } else {
    const int a = blockIdx.x - 256;             // 0..511
    const int tm = a >> 8, r = a & 255, tn = r & 63, ks = r >> 6;  // ks 0..3
    const int Na = cnt[0];
    if (tm * 128 >= Na) return;
    const int k0 = ks * 512;                    // ksteps=8 * 64
    csf512_body(xc + (size_t)tm * 128 * 2048 + k0, 2048,
                w_afc + (size_t)k0 * 8192 + tn * 128, 8192,
                8, Na - 1 - tm * 128, lds,
                Pafc + ((size_t)ks * 256 + tm * 128) * 8192 + tn * 128, 8192);
  }
}

// MERGED: text proj split-K x4 (blocks 0..255) + audio proj (blocks 256..511, csf512, split-K x8)
__global__ __launch_bounds__(512, 2) void k_sk_aproj(
    const u16* __restrict__ A, const u16* __restrict__ Bt, u16* __restrict__ Psk,
    const u16* __restrict__ t1a, const float* __restrict__ w_aproj,
    u16* __restrict__ Paprj, const int* __restrict__ cnt) {
  __shared__ u16 lds[65536];
  if (blockIdx.x < 256) {
    const int wg = xswz(blockIdx.x, 256);
    const int ks = wg >> 6, rem = wg & 63;
    const int tm = rem >> 3, tn = rem & 7;
    f32x4 acc[8][4];
    g8_acc_zero(acc);
    g8_core(A + (size_t)tm * 256 * 8192 + ks * 2048, 8192,
            Bt + (size_t)tn * 256 * 8192 + ks * 2048, 8192, 32, lds, acc);
    const int lane = threadIdx.x & 63, wid = threadIdx.x >> 6;
    const int wr = wid >> 2, wc = wid & 3;
    const int col = lane & 15, rb = (lane >> 4) * 4;
#pragma unroll
    for (int m = 0; m < 8; ++m)
#pragma unroll
      for (int n = 0; n < 4; ++n)
#pragma unroll
        for (int j = 0; j < 4; ++j) {
          int gm = tm * 256 + wr * 128 + m * 16 + rb + j;
          int gn = tn * 256 + wc * 64 + n * 16 + col;
          Psk[((size_t)ks * 2048 + gm) * 2048 + gn] = f2bf(acc[m][n][j]);
        }
  } else {
    const int a = blockIdx.x - 256;             // 0..255
    const int tm = a >> 7, r = a & 127, tn = r & 15, ks = r >> 4;  // ks 0..7
    const int Na = cnt[0];
    if (tm * 128 >= Na) return;
    const int k0 = ks * 1024;                   // ksteps=16 * 64
    csf512_body(t1a + (size_t)tm * 128 * 8192 + k0, 8192,
                w_aproj + (size_t)k0 * 2048 + tn * 128, 2048,
                16, Na - 1 - tm * 128, lds,
                Paprj + ((size_t)ks * 256 + tm * 128) * 2048 + tn * 128, 2048);
  }
}

// qkv reduce: sum 2 bf16 partials, scatter into Q/K/VT
__global__ __launch_bounds__(256) void k_red_qkv(
    const u16* __restrict__ Pq, u16* __restrict__ Q, u16* __restrict__ Kb,
    u16* __restrict__ VT) {
  const int gm = blockIdx.y;
  const int c = blockIdx.x * 1024 + threadIdx.x * 4;
  const size_t i = (size_t)gm * 4096 + c;
  u16x4 a = *(const u16x4*)&Pq[i];
  u16x4 b2 = *(const u16x4*)&Pq[(size_t)2048 * 4096 + i];
  const int b = gm >> 10, s = gm & 1023;
  u16 v[4];
#pragma unroll
  for (int j = 0; j < 4; ++j) v[j] = f2bf(bf2f(a[j]) + bf2f(b2[j]));
  const int d = c & 127;
  if (c < 2048) {
    int hh = c >> 7;
    *(u16x4*)&Q[((size_t)((b * 16 + hh) * 1024 + s)) * 128 + d] = *(u16x4*)v;
  } else if (c < 3072) {
    int kv = (c - 2048) >> 7;
    *(u16x4*)&Kb[((size_t)((b * 8 + kv) * 1024 + s)) * 128 + d] = *(u16x4*)v;
  } else {
    int kv = (c - 3072) >> 7;
#pragma unroll
    for (int j = 0; j < 4; ++j)
      VT[((size_t)((b * 8 + kv) * 128 + d + j)) * 1024 + s] = v[j];
  }
}

// =================================================================== fused flash attention
// QBLK=64: grid (16,32) = 512 blocks = 2/CU on all 256 CUs.
__device__ __forceinline__ void fa_stage128(const u16* __restrict__ G, int ldg, u16* dst,
                                            int nloads) {
  const int tid = threadIdx.x;
  for (int ld = 0; ld < nloads; ++ld) {
    int unit = ld * 256 + tid;
    int row = unit >> 4;
    int seg = (unit & 15) ^ (row & 7);
    __builtin_amdgcn_global_load_lds(
        (const __attribute__((address_space(1))) void*)(G + (size_t)row * ldg + seg * 8),
        (__attribute__((address_space(3))) void*)(dst + ld * 2048 + (tid >> 6) * 512),
        16, 0, 0);
  }
}
__device__ __forceinline__ void fa_stage64(const u16* __restrict__ G, int ldg, u16* dst,
                                           int nloads) {
  const int tid = threadIdx.x;
  for (int ld = 0; ld < nloads; ++ld) {
    int unit = ld * 256 + tid;
    int row = unit >> 3;
    int seg = (unit & 7) ^ (row & 7);
    __builtin_amdgcn_global_load_lds(
        (const __attribute__((address_space(1))) void*)(G + (size_t)row * ldg + seg * 8),
        (__attribute__((address_space(3))) void*)(dst + ld * 2048 + (tid >> 6) * 512),
        16, 0, 0);
  }
}

__global__ __launch_bounds__(256, 2) void k_fattn(
    const u16* __restrict__ Q, const u16* __restrict__ Kb, const u16* __restrict__ VT,
    u16* __restrict__ O) {
  const int tm = blockIdx.x;       // q-tile (64 rows), 0..15
  const int bh = blockIdx.y;
  const int b = bh >> 4, hq = bh & 15, kv = hq >> 1;
  __shared__ u16 lds[32768];       // 64 KB
  u16* Klds = lds;                 // [64][128]  (16 KB)
  u16* Vlds = lds + 8192;          // [2][128][64] (32 KB)
  u16* Plds = lds + 24576;         // [64][64]   (8 KB)
  const int lane = threadIdx.x & 63, wave = threadIdx.x >> 6;
  const int wm = wave * 16;
  const int lr = lane & 15, lk = lane >> 4;
  const int rb = lk * 4;
  const int cl = lr;

  const u16* Qg = Q + ((size_t)(b * 16 + hq) * 1024 + tm * 64) * 128;
  fa_stage128(Qg, 128, lds, 4);
  asm volatile("s_waitcnt vmcnt(0)" ::: "memory");
  __builtin_amdgcn_s_barrier();
  __builtin_amdgcn_sched_barrier(0);
  bf16x8 qf[4];
#pragma unroll
  for (int kk = 0; kk < 4; ++kk) {
    int row = wm + lr;
    qf[kk] = *(const bf16x8*)&lds[row * 128 + (((kk * 4 + lk) ^ (lr & 7)) * 8)];
  }
  asm volatile("s_waitcnt lgkmcnt(0)" ::: "memory");
  __builtin_amdgcn_s_barrier();
  __builtin_amdgcn_sched_barrier(0);

  const u16* Kg = Kb + (size_t)(b * 8 + kv) * 1024 * 128;
  const u16* Vg = VT + (size_t)(b * 8 + kv) * 128 * 1024;
  const int NT = tm + 1;
  fa_stage128(Kg, 128, Klds, 4);          // K_0
  fa_stage64(Vg, 1024, Vlds, 4);          // V_0

  f32x4 accO[8];
#pragma unroll
  for (int n = 0; n < 8; ++n) accO[n] = (f32x4){0.f, 0.f, 0.f, 0.f};
  float mst[4], lst[4];
#pragma unroll
  for (int i = 0; i < 4; ++i) { mst[i] = -3.0e38f; lst[i] = 0.f; }
  const float scale = 0.08838834764831845f;

  for (int t = 0; t < NT; ++t) {
    asm volatile("s_waitcnt vmcnt(0)" ::: "memory");
    __builtin_amdgcn_s_barrier();
    __builtin_amdgcn_sched_barrier(0);
    u16* Vcur = Vlds + (t & 1) * 8192;
    f32x4 accS[4];
#pragma unroll
    for (int n = 0; n < 4; ++n) accS[n] = (f32x4){0.f, 0.f, 0.f, 0.f};
#pragma unroll
    for (int kk = 0; kk < 4; ++kk) {
      bf16x8 kf[4];
#pragma unroll
      for (int n = 0; n < 4; ++n)
        kf[n] = *(const bf16x8*)&Klds[(n * 16 + lr) * 128 + (((kk * 4 + lk) ^ (lr & 7)) * 8)];
#pragma unroll
      for (int n = 0; n < 4; ++n)
        accS[n] = __builtin_amdgcn_mfma_f32_16x16x32_bf16(qf[kk], kf[n], accS[n], 0, 0, 0);
    }
    asm volatile("s_waitcnt lgkmcnt(0)" ::: "memory");
    __builtin_amdgcn_s_barrier();
    __builtin_amdgcn_sched_barrier(0);
    if (t + 1 < NT) {
      fa_stage128(Kg + (size_t)(t + 1) * 64 * 128, 128, Klds, 4);
      fa_stage64(Vg + (t + 1) * 64, 1024, Vlds + ((t + 1) & 1) * 8192, 4);
    }
    const bool dm = (t >= tm);   // diagonal tile
#pragma unroll
    for (int j = 0; j < 4; ++j) {
      const int rglob = tm * 64 + wm + rb + j;
      float v[4];
      float vmax = -3.0e38f;
#pragma unroll
      for (int n = 0; n < 4; ++n) {
        float x = accS[n][j] * scale;
        if (dm && (t * 64 + n * 16 + cl > rglob)) x = -3.0e38f;
        v[n] = x;
        vmax = fmaxf(vmax, x);
      }
#pragma unroll
      for (int o = 1; o < 16; o <<= 1) vmax = fmaxf(vmax, __shfl_xor(vmax, o));
      float mnew = fmaxf(mst[j], vmax);
      float alpha = __expf(mst[j] - mnew);
      mst[j] = mnew;
      float rs = 0.f;
      const int prow = wm + rb + j;
#pragma unroll
      for (int n = 0; n < 4; ++n) {
        float pp = __expf(v[n] - mnew);
        rs += pp;
        int col = n * 16 + cl;
        Plds[prow * 64 + (((col >> 3) ^ (prow & 7)) * 8) + (col & 7)] = f2bf(pp);
      }
#pragma unroll
      for (int o = 1; o < 16; o <<= 1) rs += __shfl_xor(rs, o);
      lst[j] = lst[j] * alpha + rs;
#pragma unroll
      for (int n = 0; n < 8; ++n) accO[n][j] *= alpha;
    }
#pragma unroll
    for (int kk = 0; kk < 2; ++kk) {
      bf16x8 pf, vf[8];
      {
        int prow = wm + lr;
        pf = *(const bf16x8*)&Plds[prow * 64 + (((kk * 4 + lk) ^ (lr & 7)) * 8)];
      }
#pragma unroll
      for (int n = 0; n < 8; ++n) {
        int d = n * 16 + lr;
        vf[n] = *(const bf16x8*)&Vcur[d * 64 + (((kk * 4 + lk) ^ (d & 7)) * 8)];
      }
#pragma unroll
      for (int n = 0; n < 8; ++n)
        accO[n] = __builtin_amdgcn_mfma_f32_16x16x32_bf16(pf, vf[n], accO[n], 0, 0, 0);
    }
  }
#pragma unroll
  for (int j = 0; j < 4; ++j) {
    float invl = 1.f / lst[j];
    int s = tm * 64 + wm + rb + j;
#pragma unroll
    for (int n = 0; n < 8; ++n) {
      int d = n * 16 + cl;
      O[(size_t)(b * 1024 + s) * 2048 + hq * 128 + d] = f2bf(accO[n][j] * invl);
    }
  }
}

// t1a = silu(sum 4 audio-fc partials)
__global__ __launch_bounds__(256) void k_red4_silu(
    const u16* __restrict__ Pp, u16* __restrict__ t1a, const int* __restrict__ cnt) {
  const int row = blockIdx.y;
  if (row >= cnt[0]) return;
  const int c = blockIdx.x * 1024 + threadIdx.x * 4;
  const size_t i = (size_t)row * 8192 + c;
  float s[4] = {0.f, 0.f, 0.f, 0.f};
#pragma unroll
  for (int k = 0; k < 4; ++k) {
    u16x4 a = *(const u16x4*)&Pp[(size_t)k * 256 * 8192 + i];
#pragma unroll
    for (int j = 0; j < 4; ++j) s[j] += bf2f(a[j]);
  }
  u16x4 ov;
#pragma unroll
  for (int j = 0; j < 4; ++j) {
    float v = s[j];
    ov[j] = f2bf(v / (1.f + __expf(-v)));
  }
  *(u16x4*)&t1a[i] = ov;
}

// ------------------------------------------------------------- RMS helpers
__device__ __forceinline__ float block_sum256(float v, float* red) {
  const int tid = threadIdx.x;
#pragma unroll
  for (int o = 32; o; o >>= 1) v += __shfl_xor(v, o);
  if ((tid & 63) == 0) red[tid >> 6] = v;
  __syncthreads();
  float r = red[0] + red[1] + red[2] + red[3];
  __syncthreads();
  return r;
}

// MERGED: weight transpose (blocks 0..22527) + embed/mask/layer-0 norm (22528..24575)
__global__ __launch_bounds__(256) void k_trans_embed(
    const float* __restrict__ w_qkv, const float* __restrict__ w_o,
    const float* __restrict__ w_fc, const float* __restrict__ w_proj,
    u16* __restrict__ WtAll,
    const int* __restrict__ ids, const float* __restrict__ vocab,
    const float* __restrict__ audio, const float* __restrict__ wt,
    const float* __restrict__ wa, float* __restrict__ h, int* __restrict__ mask,
    u16* __restrict__ x) {
  __shared__ float tile[64][65];
  const int tid = threadIdx.x;
  if (blockIdx.x < 22528) {
    int bid = blockIdx.x;
    int l = 0;
    if (bid >= 11264) { l = 1; bid -= 11264; }
    const float* src;
    u16* dst;
    int K, N, t;
    u16* WtL = WtAll + (size_t)l * 46137344;
    if (bid < 2048)       { src = w_qkv  + (size_t)l * 8388608;  dst = WtL;            K = 2048; N = 4096; t = bid; }
    else if (bid < 3072)  { src = w_o    + (size_t)l * 4194304;  dst = WtL + 8388608;  K = 2048; N = 2048; t = bid - 2048; }
    else if (bid < 7168)  { src = w_fc   + (size_t)l * 16777216; dst = WtL + 12582912; K = 2048; N = 8192; t = bid - 3072; }
    else                  { src = w_proj + (size_t)l * 16777216; dst = WtL + 29360128; K = 8192; N = 2048; t = bid - 7168; }
    const int nk = K >> 6;
    const int sb = t >> 6, w = t & 63;
    const int nsbk = nk >> 3;
    const int tk = ((sb % nsbk) << 3) + (w & 7);
    const int tn = ((sb / nsbk) << 3) + (w >> 3);
#pragma unroll
    for (int i = 0; i < 4; ++i) {
      int idx = i * 256 + tid;
      int r = idx >> 4, c4 = (idx & 15) * 4;
      f32x4 v = __builtin_nontemporal_load(
          (const f32x4*)&src[(size_t)(tk * 64 + r) * N + tn * 64 + c4]);
      tile[r][c4]     = v[0];
      tile[r][c4 + 1] = v[1];
      tile[r][c4 + 2] = v[2];
      tile[r][c4 + 3] = v[3];
    }
    __syncthreads();
#pragma unroll
    for (int i = 0; i < 2; ++i) {
      int u = i * 256 + tid;
      int n = u >> 3, seg = u & 7;
      u16x8 ov;
#pragma unroll
      for (int j = 0; j < 8; ++j) ov[j] = f2bf(tile[seg * 8 + j][n]);
      __builtin_nontemporal_store(ov,
          (u16x8*)&dst[(size_t)(tn * 64 + n) * K + tk * 64 + seg * 8]);
    }
  } else {
    const int t = blockIdx.x - 22528;
    const int id = ids[t];
    const int am = (id > 31999) ? 1 : 0;
    if (tid == 0) mask[t] = am;
    float* hr = h + (size_t)t * 2048;
    const int c0 = tid * 8;
    float4 v0, v1;
    if (!am) {
      const float4* src = (const float4*)(vocab + (size_t)id * 2048);
      v0 = src[tid * 2];
      v1 = src[tid * 2 + 1];
    } else {
      const int aid = id - 32000;
      v0 = (float4){0.f, 0.f, 0.f, 0.f};
      v1 = (float4){0.f, 0.f, 0.f, 0.f};
#pragma unroll
      for (int c = 0; c < 8; ++c) {
        const float4* ap = (const float4*)(audio + (size_t)(aid + c * 1026) * 2048);
        float4 a0 = ap[tid * 2], a1 = ap[tid * 2 + 1];
        v0.x += a0.x; v0.y += a0.y; v0.z += a0.z; v0.w += a0.w;
        v1.x += a1.x; v1.y += a1.y; v1.z += a1.z; v1.w += a1.w;
      }
    }
    ((float4*)hr)[tid * 2] = v0;
    ((float4*)hr)[tid * 2 + 1] = v1;
    const float* f0 = (const float*)&v0;
    const float* f1 = (const float*)&v1;
    float ss = 0.f;
#pragma unroll
    for (int j = 0; j < 4; ++j) ss += f0[j] * f0[j] + f1[j] * f1[j];
    float* red = &tile[0][0];
    ss = block_sum256(ss, red);
    const float inv = rsqrtf(ss * (1.0f / 2048.0f) + 1e-5f);
    const float* w = am ? wa : wt;
    u16x8 a;
#pragma unroll
    for (int j = 0; j < 8; ++j) {
      float hv = (j < 4 ? f0[j] : f1[j - 4]) * inv;
      a[j] = f2bf(hv * w[c0 + j]);
    }
    *(u16x8*)&x[(size_t)t * 2048 + c0] = a;
  }
}

// ------------------------------------------------------------- mask scan (1 block)
__global__ __launch_bounds__(256) void k_scan(
    const int* __restrict__ mask, int* __restrict__ cpos,
    int* __restrict__ cidx, int* __restrict__ cnt) {
  const int tid = threadIdx.x;
  const int lane = tid & 63, wid = tid >> 6;
  int m[8];
  int s = 0;
#pragma unroll
  for (int j = 0; j < 8; ++j) { m[j] = mask[tid * 8 + j]; s += m[j]; }
  int ps = s;
#pragma unroll
  for (int o = 1; o < 64; o <<= 1) {
    int t = __shfl_up(ps, o);
    if (lane >= o) ps += t;
  }
  __shared__ int wsum[4];
  if (lane == 63) wsum[wid] = ps;
  __syncthreads();
  int base = 0;
  for (int w = 0; w < wid; ++w) base += wsum[w];
  int run = base + ps - s;
#pragma unroll
  for (int j = 0; j < 8; ++j) {
    int row = tid * 8 + j;
    cpos[row] = run;
    if (m[j]) cidx[run] = row;
    run += m[j];
  }
  if (tid == 255) cnt[0] = run;
}

// fused: h += sum4 o-proj bf16 partials ; post-norm -> x (text) + compacted xc (audio)
__global__ __launch_bounds__(256) void k_redrms_post(
    float* __restrict__ h, const u16* __restrict__ Pp,
    const float* __restrict__ wt, const float* __restrict__ wa,
    const int* __restrict__ mask, u16* __restrict__ x, u16* __restrict__ xc,
    const int* __restrict__ cpos) {
  const int row = blockIdx.x, tid = threadIdx.x;
  const int c0 = tid * 8;
  const size_t base = (size_t)row * 2048 + c0;
  float4 a0 = *(const float4*)&h[base];
  float4 a1 = *(const float4*)&h[base + 4];
  float* fa0 = (float*)&a0;
  float* fa1 = (float*)&a1;
#pragma unroll
  for (int k = 0; k < 4; ++k) {
    u16x8 pv = *(const u16x8*)&Pp[(size_t)k * 2048 * 2048 + base];
#pragma unroll
    for (int j = 0; j < 4; ++j) fa0[j] += bf2f(pv[j]);
#pragma unroll
    for (int j = 0; j < 4; ++j) fa1[j] += bf2f(pv[4 + j]);
  }
  *(float4*)&h[base] = a0;
  *(float4*)&h[base + 4] = a1;
  float ss = 0.f;
#pragma unroll
  for (int j = 0; j < 4; ++j) ss += fa0[j] * fa0[j] + fa1[j] * fa1[j];
  __shared__ float red[4];
  ss = block_sum256(ss, red);
  const float inv = rsqrtf(ss * (1.0f / 2048.0f) + 1e-5f);
  u16x8 xv;
#pragma unroll
  for (int j = 0; j < 8; ++j) {
    float hv = (j < 4 ? fa0[j] : fa1[j - 4]) * inv;
    xv[j] = f2bf(hv * wt[c0 + j]);
  }
  *(u16x8*)&x[base] = xv;
  if (mask[row]) {
    u16x8 av;
#pragma unroll
    for (int j = 0; j < 8; ++j) {
      float hv = (j < 4 ? fa0[j] : fa1[j - 4]) * inv;
      av[j] = f2bf(hv * wa[c0 + j]);
    }
    *(u16x8*)&xc[(size_t)cpos[row] * 2048 + c0] = av;
  }
}

// fused: h += (text? sum4 proj partials : sum8 audio-proj partials via cpos) ;
//        then next input-norm (select) -> x, or final ln_f -> outf
__global__ __launch_bounds__(256) void k_redrms_ffn(
    float* __restrict__ h, const u16* __restrict__ Psk, const u16* __restrict__ Pap,
    const float* __restrict__ wt, const float* __restrict__ wa,
    const float* __restrict__ wf, const int* __restrict__ mask,
    const int* __restrict__ cpos, u16* __restrict__ x, float* __restrict__ outf, int fin) {
  const int row = blockIdx.x, tid = threadIdx.x;
  const int c0 = tid * 8;
  const size_t base = (size_t)row * 2048 + c0;
  float4 a0 = *(const float4*)&h[base];
  float4 a1 = *(const float4*)&h[base + 4];
  float* fa0 = (float*)&a0;
  float* fa1 = (float*)&a1;
  if (mask[row] == 0) {
#pragma unroll
    for (int k = 0; k < 4; ++k) {
      u16x8 pv = *(const u16x8*)&Psk[(size_t)k * 2048 * 2048 + base];
#pragma unroll
      for (int j = 0; j < 4; ++j) fa0[j] += bf2f(pv[j]);
#pragma unroll
      for (int j = 0; j < 4; ++j) fa1[j] += bf2f(pv[4 + j]);
    }
  } else {
    const size_t cb = (size_t)cpos[row] * 2048 + c0;
#pragma unroll
    for (int k = 0; k < 8; ++k) {
      u16x8 pv = *(const u16x8*)&Pap[(size_t)k * 256 * 2048 + cb];
#pragma unroll
      for (int j = 0; j < 4; ++j) fa0[j] += bf2f(pv[j]);
#pragma unroll
      for (int j = 0; j < 4; ++j) fa1[j] += bf2f(pv[4 + j]);
    }
  }
  if (!fin) {
    *(float4*)&h[base] = a0;
    *(float4*)&h[base + 4] = a1;
  }
  float ss = 0.f;
#pragma unroll
  for (int j = 0; j < 4; ++j) ss += fa0[j] * fa0[j] + fa1[j] * fa1[j];
  __shared__ float red[4];
  ss = block_sum256(ss, red);
  const float inv = rsqrtf(ss * (1.0f / 2048.0f) + 1e-5f);
  if (fin) {
    float4 o0, o1;
    float* p0 = (float*)&o0;
    float* p1 = (float*)&o1;
#pragma unroll
    for (int j = 0; j < 4; ++j) {
      p0[j] = fa0[j] * inv * wf[c0 + j];
      p1[j] = fa1[j] * inv * wf[c0 + 4 + j];
    }
    *(float4*)&outf[base] = o0;
    *(float4*)&outf[base + 4] = o1;
  } else {
    const float* w = mask[row] ? wa : wt;
    u16x8 xv;
#pragma unroll
    for (int j = 0; j < 8; ++j) {
      float hv = (j < 4 ? fa0[j] : fa1[j - 4]) * inv;
      xv[j] = f2bf(hv * w[c0 + j]);
    }
    *(u16x8*)&x[base] = xv;
  }
}

// ------------------------------------------------------------- host launch
extern "C" void kernel_launch(void* const* d_in, const int* in_sizes, int n_in,
                              void* d_out, int out_size, void* d_ws, size_t ws_size,
                              hipStream_t stream) {
  const int* ids = (const int*)d_in[0];
  const float* vocab = (const float*)d_in[1];
  const float* audio = (const float*)d_in[2];
  const float* ln_in = (const float*)d_in[3];
  const float* ln_audio_in = (const float*)d_in[4];
  const float* ln_post = (const float*)d_in[5];
  const float* ln_audio_post = (const float*)d_in[6];
  const float* w_qkv = (const float*)d_in[7];
  const float* w_o = (const float*)d_in[8];
  const float* w_fc = (const float*)d_in[9];
  const float* w_proj = (const float*)d_in[10];
  const float* w_afc = (const float*)d_in[11];
  const float* w_aproj = (const float*)d_in[12];
  const float* ln_f = (const float*)d_in[13];
  float* out = (float*)d_out;

  char* p = (char*)d_ws;
  auto alloc = [&](size_t bytes) {
    char* r = p;
    p += (bytes + 255) & ~(size_t)255;
    return r;
  };
  float* h   = (float*)alloc((size_t)2048 * 2048 * 4);
  u16* x     = (u16*)alloc((size_t)2048 * 2048 * 2);
  u16* xc    = (u16*)alloc((size_t)2048 * 2048 * 2);
  u16* o     = (u16*)alloc((size_t)2048 * 2048 * 2);
  int* mask  = (int*)alloc((size_t)2048 * 4);
  int* cpos  = (int*)alloc((size_t)2048 * 4);
  int* cidx  = (int*)alloc((size_t)2048 * 4);
  int* cnt   = (int*)alloc((size_t)64 * 4);
  u16* WtAll = (u16*)alloc((size_t)2 * 46137344 * 2);        // 184 MB: text-path transposed weights
  u16* Q     = (u16*)alloc((size_t)2 * 16 * 1024 * 128 * 2);
  u16* Kb    = (u16*)alloc((size_t)2 * 8 * 1024 * 128 * 2);
  u16* VT    = (u16*)alloc((size_t)2 * 8 * 1024 * 128 * 2);
  char* A    = alloc((size_t)128 * 1024 * 1024);             // 128 MB multi-use region
  char* Bg   = alloc((size_t)24 * 1024 * 1024);              // 24 MB region
  u16* t1    = (u16*)alloc((size_t)2048 * 8192 * 2);
  u16* t1a   = (u16*)alloc((size_t)256 * 8192 * 2);          // audio fc output (4 MB)
  // Region aliases (lifetimes disjoint in stream order), all bf16 partials:
  u16* Pq    = (u16*)A;                          // [2][2048][4096] qkv partials (33.5 MB)
  u16* Psk   = (u16*)A;                          // [4][2048][2048] o/proj partials (33.5 MB)
  u16* Pafc  = (u16*)(A + (size_t)67108864);     // [4][256][8192] audio-fc partials (16.8 MB)
  u16* Paprj = (u16*)Bg;                         // [8][256][2048] audio-proj partials (8.4 MB)
  (void)ws_size; (void)in_sizes; (void)n_in; (void)out_size;

  // merged: text-path weight transposes + embedding/mask/layer-0 norm
  k_trans_embed<<<24576, 256, 0, stream>>>(w_qkv, w_o, w_fc, w_proj, WtAll,
                                           ids, vocab, audio, ln_in, ln_audio_in, h, mask, x);
  k_scan<<<1, 256, 0, stream>>>(mask, cpos, cidx, cnt);

  for (int l = 0; l < 2; ++l) {
    u16* WtL = WtAll + (size_t)l * 46137344;
    u16* Wqkv_t  = WtL;
    u16* Wo_t    = WtL + 8388608;
    u16* Wfc_t   = WtL + 12582912;
    u16* Wproj_t = WtL + 29360128;

    // qkv: 8-phase split-K x2 -> bf16 partials -> scatter reduce
    k_gemm8_qkv<<<256, 512, 0, stream>>>(x, Wqkv_t, Pq);
    k_red_qkv<<<dim3(4, 2048), 256, 0, stream>>>(Pq, Q, Kb, VT);
    // fused flash attention (QBLK=64, full machine)
    k_fattn<<<dim3(16, 32), 256, 0, stream>>>(Q, Kb, VT, o);
    // o-proj split-K x4 -> fused reduce + residual + post-norm
    k_gemm8_sk<<<256, 512, 0, stream>>>(o, 2048, Wo_t, 2048, 8, 512, Psk);
    k_redrms_post<<<2048, 256, 0, stream>>>(h, Psk, ln_post + l * 2048,
                                            ln_audio_post + l * 2048, mask, x, xc, cpos);
    // MERGED text fc + audio fc (split-K x4)
    k_fc_afc<<<768, 512, 0, stream>>>(x, Wfc_t, t1, xc,
                                      w_afc + (size_t)l * 2048 * 8192, Pafc, cnt);
    k_red4_silu<<<dim3(8, 256), 256, 0, stream>>>(Pafc, t1a, cnt);
    // MERGED text proj (split-K x4) + audio proj (split-K x8)
    k_sk_aproj<<<512, 512, 0, stream>>>(t1, Wproj_t, Psk, t1a,
                                        w_aproj + (size_t)l * 8192 * 2048, Paprj, cnt);
    // fused: both-path residual add + (next input-norm | final ln_f)
    if (l == 0)
      k_redrms_ffn<<<2048, 256, 0, stream>>>(h, Psk, Paprj, ln_in + 2048,
                                             ln_audio_in + 2048, nullptr, mask, cpos, x,
                                             nullptr, 0);
    else
      k_redrms_ffn<<<2048, 256, 0, stream>>>(h, Psk, Paprj, nullptr, nullptr, ln_f, mask,
                                             cpos, nullptr, out, 1);
  }
}

// Round 20
// 823.380 us; speedup vs baseline: 1.0340x; 1.0340x over previous
//
#include <hip/hip_runtime.h>
#include <hip/hip_bf16.h>

typedef unsigned short u16;
typedef __attribute__((ext_vector_type(4))) float f32x4;
typedef __attribute__((ext_vector_type(8))) short bf16x8;
typedef __attribute__((ext_vector_type(8))) unsigned short u16x8;
typedef __attribute__((ext_vector_type(4))) unsigned short u16x4;

__device__ __forceinline__ u16 f2bf(float f) {
  union { float f; unsigned u; } v; v.f = f;
  unsigned r = v.u + 0x7FFFu + ((v.u >> 16) & 1u);
  return (u16)(r >> 16);
}
__device__ __forceinline__ float bf2f(u16 v) {
  union { float f; unsigned u; } x; x.u = (unsigned)v << 16; return x.f;
}

__device__ __forceinline__ int xswz(int wg, int n) {  // bijective XCD swizzle, n%8==0
  return (wg & 7) * (n >> 3) + (wg >> 3);
}

// =================================================================== 8-phase 256^2 GEMM core
__device__ __forceinline__ void g8_stage_half(
    const u16* __restrict__ G, int ldg, int tile, int half, u16* ldsbase) {
  const int tid = threadIdx.x;
#pragma unroll
  for (int load = 0; load < 2; ++load) {
    int unit = load * 512 + tid;
    int row = unit >> 3;
    int seg = (unit & 7) ^ ((unit >> 3) & 7);  // pre-swizzled source segment
    __builtin_amdgcn_global_load_lds(
        (const __attribute__((address_space(1))) void*)(G + (size_t)(half * 128 + row) * ldg + tile * 64 + seg * 8),
        (__attribute__((address_space(3))) void*)(ldsbase + half * 8192 + load * 4096 + (tid >> 6) * 512),
        16, 0, 0);
  }
}

__device__ __forceinline__ void g8_core(
    const u16* __restrict__ A, int lda, const u16* __restrict__ Bt, int ldb,
    int NT, u16* lds, f32x4 acc[8][4]) {
  const int tid = threadIdx.x;
  const int lane = tid & 63;
  const int wid = tid >> 6;
  const int wr = wid >> 2, wc = wid & 3;
  const int lr = lane & 15;
  const int lk4 = lane >> 4;
  const int sw = lane & 7;
  const int off0 = ((lk4 ^ sw) * 8);
  const int off1 = (((4 + lk4) ^ sw) * 8);

  u16* ldsA = lds;           // [buf][half][128][64]
  u16* ldsB = lds + 32768;

  g8_stage_half(A, lda, 0, 0, ldsA);
  g8_stage_half(A, lda, 0, 1, ldsA);
  g8_stage_half(Bt, ldb, 0, 0, ldsB);
  g8_stage_half(Bt, ldb, 0, 1, ldsB);
  if (NT > 1) {
    g8_stage_half(Bt, ldb, 1, 0, ldsB + 16384);
    g8_stage_half(Bt, ldb, 1, 1, ldsB + 16384);
  }
  asm volatile("s_waitcnt vmcnt(4)" ::: "memory");
  __builtin_amdgcn_s_barrier();
  __builtin_amdgcn_sched_barrier(0);

  for (int g = 0; g < NT; ++g) {
    const int buf = g & 1;
    const u16* cA = ldsA + buf * 16384 + wr * 8192;
    const u16* cB = ldsB + buf * 16384;
    bf16x8 bv[4][2];
#pragma unroll
    for (int p = 0; p < 4; ++p) {
      bf16x8 av[2][2];
      if (p == 0) {
#pragma unroll
        for (int n = 0; n < 4; ++n) {
          int rg = wc * 64 + n * 16 + lr;
          const u16* rbase = &cB[(rg >> 7) * 8192 + (rg & 127) * 64];
          bv[n][0] = *(const bf16x8*)&rbase[off0];
          bv[n][1] = *(const bf16x8*)&rbase[off1];
        }
      }
#pragma unroll
      for (int m2 = 0; m2 < 2; ++m2) {
        const u16* rbase = &cA[((p * 2 + m2) * 16 + lr) * 64];
        av[m2][0] = *(const bf16x8*)&rbase[off0];
        av[m2][1] = *(const bf16x8*)&rbase[off1];
      }

      if (p == 0 && g + 1 < NT) g8_stage_half(A, lda, g + 1, 0, ldsA + ((g + 1) & 1) * 16384);
      if (p == 1 && g + 1 < NT) g8_stage_half(A, lda, g + 1, 1, ldsA + ((g + 1) & 1) * 16384);
      if (p == 2 && g + 2 < NT) g8_stage_half(Bt, ldb, g + 2, 0, ldsB + buf * 16384);
      if (p == 3) {
        if (g + 2 < NT) {
          g8_stage_half(Bt, ldb, g + 2, 1, ldsB + buf * 16384);
          asm volatile("s_waitcnt vmcnt(4)" ::: "memory");
        } else if (g + 1 < NT) {
          asm volatile("s_waitcnt vmcnt(0)" ::: "memory");
        }
      }
      __builtin_amdgcn_s_barrier();
      asm volatile("s_waitcnt lgkmcnt(0)" ::: "memory");
      __builtin_amdgcn_sched_barrier(0);
      __builtin_amdgcn_s_setprio(1);
#pragma unroll
      for (int m2 = 0; m2 < 2; ++m2)
#pragma unroll
        for (int n = 0; n < 4; ++n)
#pragma unroll
          for (int kk = 0; kk < 2; ++kk)
            acc[p * 2 + m2][n] = __builtin_amdgcn_mfma_f32_16x16x32_bf16(
                av[m2][kk], bv[n][kk], acc[p * 2 + m2][n], 0, 0, 0);
      __builtin_amdgcn_s_setprio(0);
      __builtin_amdgcn_sched_barrier(0);
      __builtin_amdgcn_s_barrier();
    }
  }
}

__device__ __forceinline__ void g8_acc_zero(f32x4 acc[8][4]) {
#pragma unroll
  for (int m = 0; m < 8; ++m)
#pragma unroll
    for (int n = 0; n < 4; ++n)
      acc[m][n] = (f32x4){0.f, 0.f, 0.f, 0.f};
}

__device__ __forceinline__ void acc_zero4(f32x4 acc[4][4]) {
#pragma unroll
  for (int m = 0; m < 4; ++m)
#pragma unroll
    for (int n = 0; n < 4; ++n)
      acc[m][n] = (f32x4){0.f, 0.f, 0.f, 0.f};
}

// ------------------------------------------------------------------- csf512
// 512-thread compacted f32-W audio GEMM (128x128 tile) for merged dispatches.
__device__ __forceinline__ void csf512_body(
    const u16* __restrict__ Ab, int lda, const float* __restrict__ Wb, int ldw,
    int ksteps, int amax, u16* lds, u16* __restrict__ Pout, int ldc) {
  u16* sA = lds;
  u16* sB = lds + 16384;
  const int tid = threadIdx.x;
  const int wave = tid >> 6, lane = tid & 63;
  const int lr = lane & 15, lk4 = lane >> 4, sw = lane & 7;
  const int off0 = ((lk4 ^ sw) * 8), off1 = (((4 + lk4) ^ sw) * 8);
  const int srow = tid >> 3;
  const int ssw = (tid & 7) ^ ((tid >> 3) & 7);
  const int kb = tid >> 5;
  const int bn4 = (tid & 31) * 4;
  f32x4 breg[4];

  auto stageA = [&](int buf, int kt) {
    const int kk0 = kt * 64;
#pragma unroll
    for (int i = 0; i < 2; ++i) {
      int ra = i * 64 + srow; if (ra > amax) ra = amax;
      __builtin_amdgcn_global_load_lds(
          (const __attribute__((address_space(1))) void*)(Ab + (size_t)ra * lda + kk0 + ssw * 8),
          (__attribute__((address_space(3))) void*)(sA + buf * 8192 + i * 4096 + wave * 512),
          16, 0, 0);
    }
  };
  auto loadB = [&](int kt) {
#pragma unroll
    for (int i = 0; i < 4; ++i) {
      int kk = kt * 64 + i * 16 + kb;
      breg[i] = __builtin_nontemporal_load((const f32x4*)&Wb[(size_t)kk * ldw + bn4]);
    }
  };
  auto writeB = [&](int buf) {
    u16* dB = sB + buf * 8192;
#pragma unroll
    for (int i = 0; i < 4; ++i) {
      int kk = i * 16 + kb;
#pragma unroll
      for (int j = 0; j < 4; ++j) {
        int n = bn4 + j;
        dB[n * 64 + (((kk >> 3) ^ (n & 7)) * 8) + (kk & 7)] = f2bf(breg[i][j]);
      }
    }
  };

  f32x4 acc[4][4];
  acc_zero4(acc);

  stageA(0, 0);
  loadB(0);
  asm volatile("s_waitcnt vmcnt(0)" ::: "memory");
  writeB(0);
  asm volatile("s_waitcnt lgkmcnt(0)" ::: "memory");
  __builtin_amdgcn_s_barrier();
  __builtin_amdgcn_sched_barrier(0);

  const int wm = (wave >> 1) * 64, wn = (wave & 1) * 64;
  for (int kt = 0; kt < ksteps; ++kt) {
    const int cur = kt & 1;
    if (kt + 1 < ksteps) { stageA(cur ^ 1, kt + 1); loadB(kt + 1); }
    if (wave < 4) {
      const u16* cA = sA + cur * 8192;
      const u16* cB = sB + cur * 8192;
#pragma unroll
      for (int kk = 0; kk < 2; ++kk) {
        const int off = kk ? off1 : off0;
        bf16x8 av[4], bv[4];
#pragma unroll
        for (int m = 0; m < 4; ++m)
          av[m] = *(const bf16x8*)&cA[(wm + m * 16 + lr) * 64 + off];
#pragma unroll
        for (int n = 0; n < 4; ++n)
          bv[n] = *(const bf16x8*)&cB[(wn + n * 16 + lr) * 64 + off];
#pragma unroll
        for (int m = 0; m < 4; ++m)
#pragma unroll
          for (int n = 0; n < 4; ++n)
            acc[m][n] = __builtin_amdgcn_mfma_f32_16x16x32_bf16(av[m], bv[n], acc[m][n], 0, 0, 0);
      }
    }
    asm volatile("s_waitcnt vmcnt(0)" ::: "memory");
    if (kt + 1 < ksteps) writeB(cur ^ 1);
    asm volatile("s_waitcnt lgkmcnt(0)" ::: "memory");
    __builtin_amdgcn_s_barrier();
    __builtin_amdgcn_sched_barrier(0);
  }
  if (wave < 4) {
    const int col = lane & 15, rb = (lane >> 4) * 4;
#pragma unroll
    for (int m = 0; m < 4; ++m)
#pragma unroll
      for (int n = 0; n < 4; ++n)
#pragma unroll
        for (int j = 0; j < 4; ++j)
          Pout[(size_t)(wm + m * 16 + rb + j) * ldc + wn + n * 16 + col] = f2bf(acc[m][n][j]);
  }
}

// qkv split-K x2 -> bf16 partials [2][2048][4096]
__global__ __launch_bounds__(512, 2) void k_gemm8_qkv(
    const u16* __restrict__ A, const u16* __restrict__ Bt, u16* __restrict__ Pq) {
  __shared__ u16 lds[65536];
  const int wg = xswz(blockIdx.x, 256);
  const int ks = wg >> 7, rem = wg & 127;
  const int tm = rem >> 4, tn = rem & 15;
  f32x4 acc[8][4];
  g8_acc_zero(acc);
  g8_core(A + (size_t)tm * 256 * 2048 + ks * 1024, 2048,
          Bt + (size_t)tn * 256 * 2048 + ks * 1024, 2048, 16, lds, acc);
  const int lane = threadIdx.x & 63, wid = threadIdx.x >> 6;
  const int wr = wid >> 2, wc = wid & 3;
  const int col = lane & 15, rb = (lane >> 4) * 4;
#pragma unroll
  for (int m = 0; m < 8; ++m)
#pragma unroll
    for (int n = 0; n < 4; ++n)
#pragma unroll
      for (int j = 0; j < 4; ++j) {
        int gm = tm * 256 + wr * 128 + m * 16 + rb + j;
        int gn = tn * 256 + wc * 64 + n * 16 + col;
        Pq[((size_t)ks * 2048 + gm) * 4096 + gn] = f2bf(acc[m][n][j]);
      }
}

// o-proj split-K x4 -> bf16 partials [4][2048][2048]
__global__ __launch_bounds__(512, 2) void k_gemm8_sk(
    const u16* __restrict__ A, int lda, const u16* __restrict__ Bt, int ldb,
    int NT, int koff, u16* __restrict__ Pp) {
  __shared__ u16 lds[65536];
  const int wg = xswz(blockIdx.x, 256);
  const int ks = wg >> 6, rem = wg & 63;
  const int tm = rem >> 3, tn = rem & 7;
  f32x4 acc[8][4];
  g8_acc_zero(acc);
  g8_core(A + (size_t)tm * 256 * lda + ks * koff, lda,
          Bt + (size_t)tn * 256 * ldb + ks * koff, ldb, NT, lds, acc);
  const int lane = threadIdx.x & 63, wid = threadIdx.x >> 6;
  const int wr = wid >> 2, wc = wid & 3;
  const int col = lane & 15, rb = (lane >> 4) * 4;
#pragma unroll
  for (int m = 0; m < 8; ++m)
#pragma unroll
    for (int n = 0; n < 4; ++n)
#pragma unroll
      for (int j = 0; j < 4; ++j) {
        int gm = tm * 256 + wr * 128 + m * 16 + rb + j;
        int gn = tn * 256 + wc * 64 + n * 16 + col;
        Pp[((size_t)ks * 2048 + gm) * 2048 + gn] = f2bf(acc[m][n][j]);
      }
}

// MERGED: text fc (blocks 0..255) + audio fc (blocks 256..1279, csf512, split-K x8)
__global__ __launch_bounds__(512, 2) void k_fc_afc(
    const u16* __restrict__ A, const u16* __restrict__ Bt, u16* __restrict__ Cb,
    const u16* __restrict__ xc, const float* __restrict__ w_afc,
    u16* __restrict__ Pafc, const int* __restrict__ cnt) {
  __shared__ u16 lds[65536];
  if (blockIdx.x < 256) {
    const int wg = xswz(blockIdx.x, 256);
    const int tm = wg >> 5, tn = wg & 31;
    f32x4 acc[8][4];
    g8_acc_zero(acc);
    g8_core(A + (size_t)tm * 256 * 2048, 2048, Bt + (size_t)tn * 256 * 2048, 2048, 32, lds, acc);
    const int lane = threadIdx.x & 63, wid = threadIdx.x >> 6;
    const int wr = wid >> 2, wc = wid & 3;
    const int col = lane & 15, rb = (lane >> 4) * 4;
#pragma unroll
    for (int m = 0; m < 8; ++m)
#pragma unroll
      for (int n = 0; n < 4; ++n)
#pragma unroll
        for (int j = 0; j < 4; ++j) {
          int gm = tm * 256 + wr * 128 + m * 16 + rb + j;
          int gn = tn * 256 + wc * 64 + n * 16 + col;
          float v = acc[m][n][j];
          Cb[(size_t)gm * 8192 + gn] = f2bf(v / (1.f + __expf(-v)));
        }
  } else {
    const int a = blockIdx.x - 256;             // 0..1023
    const int tm = a >> 9, r = a & 511, tn = r & 63, ks = r >> 6;  // ks 0..7
    const int Na = cnt[0];
    if (tm * 128 >= Na) return;
    const int k0 = ks * 256;                    // ksteps=4 * 64
    csf512_body(xc + (size_t)tm * 128 * 2048 + k0, 2048,
                w_afc + (size_t)k0 * 8192 + tn * 128, 8192,
                4, Na - 1 - tm * 128, lds,
                Pafc + ((size_t)ks * 256 + tm * 128) * 8192 + tn * 128, 8192);
  }
}

// MERGED: text proj split-K x4 (blocks 0..255) + audio proj (blocks 256..767, csf512, split-K x16)
__global__ __launch_bounds__(512, 2) void k_sk_aproj(
    const u16* __restrict__ A, const u16* __restrict__ Bt, u16* __restrict__ Psk,
    const u16* __restrict__ t1a, const float* __restrict__ w_aproj,
    u16* __restrict__ Paprj, const int* __restrict__ cnt) {
  __shared__ u16 lds[65536];
  if (blockIdx.x < 256) {
    const int wg = xswz(blockIdx.x, 256);
    const int ks = wg >> 6, rem = wg & 63;
    const int tm = rem >> 3, tn = rem & 7;
    f32x4 acc[8][4];
    g8_acc_zero(acc);
    g8_core(A + (size_t)tm * 256 * 8192 + ks * 2048, 8192,
            Bt + (size_t)tn * 256 * 8192 + ks * 2048, 8192, 32, lds, acc);
    const int lane = threadIdx.x & 63, wid = threadIdx.x >> 6;
    const int wr = wid >> 2, wc = wid & 3;
    const int col = lane & 15, rb = (lane >> 4) * 4;
#pragma unroll
    for (int m = 0; m < 8; ++m)
#pragma unroll
      for (int n = 0; n < 4; ++n)
#pragma unroll
        for (int j = 0; j < 4; ++j) {
          int gm = tm * 256 + wr * 128 + m * 16 + rb + j;
          int gn = tn * 256 + wc * 64 + n * 16 + col;
          Psk[((size_t)ks * 2048 + gm) * 2048 + gn] = f2bf(acc[m][n][j]);
        }
  } else {
    const int a = blockIdx.x - 256;             // 0..511
    const int tm = a >> 8, r = a & 255, tn = r & 15, ks = r >> 4;  // ks 0..15
    const int Na = cnt[0];
    if (tm * 128 >= Na) return;
    const int k0 = ks * 512;                    // ksteps=8 * 64
    csf512_body(t1a + (size_t)tm * 128 * 8192 + k0, 8192,
                w_aproj + (size_t)k0 * 2048 + tn * 128, 2048,
                8, Na - 1 - tm * 128, lds,
                Paprj + ((size_t)ks * 256 + tm * 128) * 2048 + tn * 128, 2048);
  }
}

// qkv reduce: sum 2 bf16 partials, scatter into Q/K/VT
__global__ __launch_bounds__(256) void k_red_qkv(
    const u16* __restrict__ Pq, u16* __restrict__ Q, u16* __restrict__ Kb,
    u16* __restrict__ VT) {
  const int gm = blockIdx.y;
  const int c = blockIdx.x * 1024 + threadIdx.x * 4;
  const size_t i = (size_t)gm * 4096 + c;
  u16x4 a = *(const u16x4*)&Pq[i];
  u16x4 b2 = *(const u16x4*)&Pq[(size_t)2048 * 4096 + i];
  const int b = gm >> 10, s = gm & 1023;
  u16 v[4];
#pragma unroll
  for (int j = 0; j < 4; ++j) v[j] = f2bf(bf2f(a[j]) + bf2f(b2[j]));
  const int d = c & 127;
  if (c < 2048) {
    int hh = c >> 7;
    *(u16x4*)&Q[((size_t)((b * 16 + hh) * 1024 + s)) * 128 + d] = *(u16x4*)v;
  } else if (c < 3072) {
    int kv = (c - 2048) >> 7;
    *(u16x4*)&Kb[((size_t)((b * 8 + kv) * 1024 + s)) * 128 + d] = *(u16x4*)v;
  } else {
    int kv = (c - 3072) >> 7;
#pragma unroll
    for (int j = 0; j < 4; ++j)
      VT[((size_t)((b * 8 + kv) * 128 + d + j)) * 1024 + s] = v[j];
  }
}

// =================================================================== fused flash attention
// QBLK=64: grid (16,32) = 512 blocks = 2/CU on all 256 CUs.
__device__ __forceinline__ void fa_stage128(const u16* __restrict__ G, int ldg, u16* dst,
                                            int nloads) {
  const int tid = threadIdx.x;
  for (int ld = 0; ld < nloads; ++ld) {
    int unit = ld * 256 + tid;
    int row = unit >> 4;
    int seg = (unit & 15) ^ (row & 7);
    __builtin_amdgcn_global_load_lds(
        (const __attribute__((address_space(1))) void*)(G + (size_t)row * ldg + seg * 8),
        (__attribute__((address_space(3))) void*)(dst + ld * 2048 + (tid >> 6) * 512),
        16, 0, 0);
  }
}
__device__ __forceinline__ void fa_stage64(const u16* __restrict__ G, int ldg, u16* dst,
                                           int nloads) {
  const int tid = threadIdx.x;
  for (int ld = 0; ld < nloads; ++ld) {
    int unit = ld * 256 + tid;
    int row = unit >> 3;
    int seg = (unit & 7) ^ (row & 7);
    __builtin_amdgcn_global_load_lds(
        (const __attribute__((address_space(1))) void*)(G + (size_t)row * ldg + seg * 8),
        (__attribute__((address_space(3))) void*)(dst + ld * 2048 + (tid >> 6) * 512),
        16, 0, 0);
  }
}

__global__ __launch_bounds__(256, 2) void k_fattn(
    const u16* __restrict__ Q, const u16* __restrict__ Kb, const u16* __restrict__ VT,
    u16* __restrict__ O) {
  const int tm = blockIdx.x;       // q-tile (64 rows), 0..15
  const int bh = blockIdx.y;
  const int b = bh >> 4, hq = bh & 15, kv = hq >> 1;
  __shared__ u16 lds[32768];       // 64 KB
  u16* Klds = lds;                 // [64][128]  (16 KB)
  u16* Vlds = lds + 8192;          // [2][128][64] (32 KB)
  u16* Plds = lds + 24576;         // [64][64]   (8 KB)
  const int lane = threadIdx.x & 63, wave = threadIdx.x >> 6;
  const int wm = wave * 16;
  const int lr = lane & 15, lk = lane >> 4;
  const int rb = lk * 4;
  const int cl = lr;

  const u16* Qg = Q + ((size_t)(b * 16 + hq) * 1024 + tm * 64) * 128;
  fa_stage128(Qg, 128, lds, 4);
  asm volatile("s_waitcnt vmcnt(0)" ::: "memory");
  __builtin_amdgcn_s_barrier();
  __builtin_amdgcn_sched_barrier(0);
  bf16x8 qf[4];
#pragma unroll
  for (int kk = 0; kk < 4; ++kk) {
    int row = wm + lr;
    qf[kk] = *(const bf16x8*)&lds[row * 128 + (((kk * 4 + lk) ^ (lr & 7)) * 8)];
  }
  asm volatile("s_waitcnt lgkmcnt(0)" ::: "memory");
  __builtin_amdgcn_s_barrier();
  __builtin_amdgcn_sched_barrier(0);

  const u16* Kg = Kb + (size_t)(b * 8 + kv) * 1024 * 128;
  const u16* Vg = VT + (size_t)(b * 8 + kv) * 128 * 1024;
  const int NT = tm + 1;
  fa_stage128(Kg, 128, Klds, 4);          // K_0
  fa_stage64(Vg, 1024, Vlds, 4);          // V_0

  f32x4 accO[8];
#pragma unroll
  for (int n = 0; n < 8; ++n) accO[n] = (f32x4){0.f, 0.f, 0.f, 0.f};
  float mst[4], lst[4];
#pragma unroll
  for (int i = 0; i < 4; ++i) { mst[i] = -3.0e38f; lst[i] = 0.f; }
  const float scale = 0.08838834764831845f;

  for (int t = 0; t < NT; ++t) {
    asm volatile("s_waitcnt vmcnt(0)" ::: "memory");
    __builtin_amdgcn_s_barrier();
    __builtin_amdgcn_sched_barrier(0);
    u16* Vcur = Vlds + (t & 1) * 8192;
    f32x4 accS[4];
#pragma unroll
    for (int n = 0; n < 4; ++n) accS[n] = (f32x4){0.f, 0.f, 0.f, 0.f};
#pragma unroll
    for (int kk = 0; kk < 4; ++kk) {
      bf16x8 kf[4];
#pragma unroll
      for (int n = 0; n < 4; ++n)
        kf[n] = *(const bf16x8*)&Klds[(n * 16 + lr) * 128 + (((kk * 4 + lk) ^ (lr & 7)) * 8)];
#pragma unroll
      for (int n = 0; n < 4; ++n)
        accS[n] = __builtin_amdgcn_mfma_f32_16x16x32_bf16(qf[kk], kf[n], accS[n], 0, 0, 0);
    }
    asm volatile("s_waitcnt lgkmcnt(0)" ::: "memory");
    __builtin_amdgcn_s_barrier();
    __builtin_amdgcn_sched_barrier(0);
    if (t + 1 < NT) {
      fa_stage128(Kg + (size_t)(t + 1) * 64 * 128, 128, Klds, 4);
      fa_stage64(Vg + (t + 1) * 64, 1024, Vlds + ((t + 1) & 1) * 8192, 4);
    }
    const bool dm = (t >= tm);   // diagonal tile
#pragma unroll
    for (int j = 0; j < 4; ++j) {
      const int rglob = tm * 64 + wm + rb + j;
      float v[4];
      float vmax = -3.0e38f;
#pragma unroll
      for (int n = 0; n < 4; ++n) {
        float x = accS[n][j] * scale;
        if (dm && (t * 64 + n * 16 + cl > rglob)) x = -3.0e38f;
        v[n] = x;
        vmax = fmaxf(vmax, x);
      }
#pragma unroll
      for (int o = 1; o < 16; o <<= 1) vmax = fmaxf(vmax, __shfl_xor(vmax, o));
      float mnew = fmaxf(mst[j], vmax);
      float alpha = __expf(mst[j] - mnew);
      mst[j] = mnew;
      float rs = 0.f;
      const int prow = wm + rb + j;
#pragma unroll
      for (int n = 0; n < 4; ++n) {
        float pp = __expf(v[n] - mnew);
        rs += pp;
        int col = n * 16 + cl;
        Plds[prow * 64 + (((col >> 3) ^ (prow & 7)) * 8) + (col & 7)] = f2bf(pp);
      }
#pragma unroll
      for (int o = 1; o < 16; o <<= 1) rs += __shfl_xor(rs, o);
      lst[j] = lst[j] * alpha + rs;
#pragma unroll
      for (int n = 0; n < 8; ++n) accO[n][j] *= alpha;
    }
#pragma unroll
    for (int kk = 0; kk < 2; ++kk) {
      bf16x8 pf, vf[8];
      {
        int prow = wm + lr;
        pf = *(const bf16x8*)&Plds[prow * 64 + (((kk * 4 + lk) ^ (lr & 7)) * 8)];
      }
#pragma unroll
      for (int n = 0; n < 8; ++n) {
        int d = n * 16 + lr;
        vf[n] = *(const bf16x8*)&Vcur[d * 64 + (((kk * 4 + lk) ^ (d & 7)) * 8)];
      }
#pragma unroll
      for (int n = 0; n < 8; ++n)
        accO[n] = __builtin_amdgcn_mfma_f32_16x16x32_bf16(pf, vf[n], accO[n], 0, 0, 0);
    }
  }
#pragma unroll
  for (int j = 0; j < 4; ++j) {
    float invl = 1.f / lst[j];
    int s = tm * 64 + wm + rb + j;
#pragma unroll
    for (int n = 0; n < 8; ++n) {
      int d = n * 16 + cl;
      O[(size_t)(b * 1024 + s) * 2048 + hq * 128 + d] = f2bf(accO[n][j] * invl);
    }
  }
}

// t1a = silu(sum 8 audio-fc partials)
__global__ __launch_bounds__(256) void k_red8_silu(
    const u16* __restrict__ Pp, u16* __restrict__ t1a, const int* __restrict__ cnt) {
  const int row = blockIdx.y;
  if (row >= cnt[0]) return;
  const int c = blockIdx.x * 1024 + threadIdx.x * 4;
  const size_t i = (size_t)row * 8192 + c;
  float s[4] = {0.f, 0.f, 0.f, 0.f};
#pragma unroll
  for (int k = 0; k < 8; ++k) {
    u16x4 a = *(const u16x4*)&Pp[(size_t)k * 256 * 8192 + i];
#pragma unroll
    for (int j = 0; j < 4; ++j) s[j] += bf2f(a[j]);
  }
  u16x4 ov;
#pragma unroll
  for (int j = 0; j < 4; ++j) {
    float v = s[j];
    ov[j] = f2bf(v / (1.f + __expf(-v)));
  }
  *(u16x4*)&t1a[i] = ov;
}

// ------------------------------------------------------------- RMS helpers
__device__ __forceinline__ float block_sum256(float v, float* red) {
  const int tid = threadIdx.x;
#pragma unroll
  for (int o = 32; o; o >>= 1) v += __shfl_xor(v, o);
  if ((tid & 63) == 0) red[tid >> 6] = v;
  __syncthreads();
  float r = red[0] + red[1] + red[2] + red[3];
  __syncthreads();
  return r;
}

// MERGED: weight transpose (blocks 0..22527) + embed/mask/layer-0 norm (22528..24575)
__global__ __launch_bounds__(256) void k_trans_embed(
    const float* __restrict__ w_qkv, const float* __restrict__ w_o,
    const float* __restrict__ w_fc, const float* __restrict__ w_proj,
    u16* __restrict__ WtAll,
    const int* __restrict__ ids, const float* __restrict__ vocab,
    const float* __restrict__ audio, const float* __restrict__ wt,
    const float* __restrict__ wa, float* __restrict__ h, int* __restrict__ mask,
    u16* __restrict__ x) {
  __shared__ float tile[64][65];
  const int tid = threadIdx.x;
  if (blockIdx.x < 22528) {
    int bid = blockIdx.x;
    int l = 0;
    if (bid >= 11264) { l = 1; bid -= 11264; }
    const float* src;
    u16* dst;
    int K, N, t;
    u16* WtL = WtAll + (size_t)l * 46137344;
    if (bid < 2048)       { src = w_qkv  + (size_t)l * 8388608;  dst = WtL;            K = 2048; N = 4096; t = bid; }
    else if (bid < 3072)  { src = w_o    + (size_t)l * 4194304;  dst = WtL + 8388608;  K = 2048; N = 2048; t = bid - 2048; }
    else if (bid < 7168)  { src = w_fc   + (size_t)l * 16777216; dst = WtL + 12582912; K = 2048; N = 8192; t = bid - 3072; }
    else                  { src = w_proj + (size_t)l * 16777216; dst = WtL + 29360128; K = 8192; N = 2048; t = bid - 7168; }
    const int nk = K >> 6;
    const int sb = t >> 6, w = t & 63;
    const int nsbk = nk >> 3;
    const int tk = ((sb % nsbk) << 3) + (w & 7);
    const int tn = ((sb / nsbk) << 3) + (w >> 3);
#pragma unroll
    for (int i = 0; i < 4; ++i) {
      int idx = i * 256 + tid;
      int r = idx >> 4, c4 = (idx & 15) * 4;
      f32x4 v = __builtin_nontemporal_load(
          (const f32x4*)&src[(size_t)(tk * 64 + r) * N + tn * 64 + c4]);
      tile[r][c4]     = v[0];
      tile[r][c4 + 1] = v[1];
      tile[r][c4 + 2] = v[2];
      tile[r][c4 + 3] = v[3];
    }
    __syncthreads();
#pragma unroll
    for (int i = 0; i < 2; ++i) {
      int u = i * 256 + tid;
      int n = u >> 3, seg = u & 7;
      u16x8 ov;
#pragma unroll
      for (int j = 0; j < 8; ++j) ov[j] = f2bf(tile[seg * 8 + j][n]);
      __builtin_nontemporal_store(ov,
          (u16x8*)&dst[(size_t)(tn * 64 + n) * K + tk * 64 + seg * 8]);
    }
  } else {
    const int t = blockIdx.x - 22528;
    const int id = ids[t];
    const int am = (id > 31999) ? 1 : 0;
    if (tid == 0) mask[t] = am;
    float* hr = h + (size_t)t * 2048;
    const int c0 = tid * 8;
    float4 v0, v1;
    if (!am) {
      const float4* src = (const float4*)(vocab + (size_t)id * 2048);
      v0 = src[tid * 2];
      v1 = src[tid * 2 + 1];
    } else {
      const int aid = id - 32000;
      v0 = (float4){0.f, 0.f, 0.f, 0.f};
      v1 = (float4){0.f, 0.f, 0.f, 0.f};
#pragma unroll
      for (int c = 0; c < 8; ++c) {
        const float4* ap = (const float4*)(audio + (size_t)(aid + c * 1026) * 2048);
        float4 a0 = ap[tid * 2], a1 = ap[tid * 2 + 1];
        v0.x += a0.x; v0.y += a0.y; v0.z += a0.z; v0.w += a0.w;
        v1.x += a1.x; v1.y += a1.y; v1.z += a1.z; v1.w += a1.w;
      }
    }
    ((float4*)hr)[tid * 2] = v0;
    ((float4*)hr)[tid * 2 + 1] = v1;
    const float* f0 = (const float*)&v0;
    const float* f1 = (const float*)&v1;
    float ss = 0.f;
#pragma unroll
    for (int j = 0; j < 4; ++j) ss += f0[j] * f0[j] + f1[j] * f1[j];
    float* red = &tile[0][0];
    ss = block_sum256(ss, red);
    const float inv = rsqrtf(ss * (1.0f / 2048.0f) + 1e-5f);
    const float* w = am ? wa : wt;
    u16x8 a;
#pragma unroll
    for (int j = 0; j < 8; ++j) {
      float hv = (j < 4 ? f0[j] : f1[j - 4]) * inv;
      a[j] = f2bf(hv * w[c0 + j]);
    }
    *(u16x8*)&x[(size_t)t * 2048 + c0] = a;
  }
}

// ------------------------------------------------------------- mask scan (1 block)
__global__ __launch_bounds__(256) void k_scan(
    const int* __restrict__ mask, int* __restrict__ cpos,
    int* __restrict__ cidx, int* __restrict__ cnt) {
  const int tid = threadIdx.x;
  const int lane = tid & 63, wid = tid >> 6;
  int m[8];
  int s = 0;
#pragma unroll
  for (int j = 0; j < 8; ++j) { m[j] = mask[tid * 8 + j]; s += m[j]; }
  int ps = s;
#pragma unroll
  for (int o = 1; o < 64; o <<= 1) {
    int t = __shfl_up(ps, o);
    if (lane >= o) ps += t;
  }
  __shared__ int wsum[4];
  if (lane == 63) wsum[wid] = ps;
  __syncthreads();
  int base = 0;
  for (int w = 0; w < wid; ++w) base += wsum[w];
  int run = base + ps - s;
#pragma unroll
  for (int j = 0; j < 8; ++j) {
    int row = tid * 8 + j;
    cpos[row] = run;
    if (m[j]) cidx[run] = row;
    run += m[j];
  }
  if (tid == 255) cnt[0] = run;
}

// fused: h += sum4 o-proj bf16 partials ; post-norm -> x (text) + compacted xc (audio)
__global__ __launch_bounds__(256) void k_redrms_post(
    float* __restrict__ h, const u16* __restrict__ Pp,
    const float* __restrict__ wt, const float* __restrict__ wa,
    const int* __restrict__ mask, u16* __restrict__ x, u16* __restrict__ xc,
    const int* __restrict__ cpos) {
  const int row = blockIdx.x, tid = threadIdx.x;
  const int c0 = tid * 8;
  const size_t base = (size_t)row * 2048 + c0;
  float4 a0 = *(const float4*)&h[base];
  float4 a1 = *(const float4*)&h[base + 4];
  float* fa0 = (float*)&a0;
  float* fa1 = (float*)&a1;
#pragma unroll
  for (int k = 0; k < 4; ++k) {
    u16x8 pv = *(const u16x8*)&Pp[(size_t)k * 2048 * 2048 + base];
#pragma unroll
    for (int j = 0; j < 4; ++j) fa0[j] += bf2f(pv[j]);
#pragma unroll
    for (int j = 0; j < 4; ++j) fa1[j] += bf2f(pv[4 + j]);
  }
  *(float4*)&h[base] = a0;
  *(float4*)&h[base + 4] = a1;
  float ss = 0.f;
#pragma unroll
  for (int j = 0; j < 4; ++j) ss += fa0[j] * fa0[j] + fa1[j] * fa1[j];
  __shared__ float red[4];
  ss = block_sum256(ss, red);
  const float inv = rsqrtf(ss * (1.0f / 2048.0f) + 1e-5f);
  u16x8 xv;
#pragma unroll
  for (int j = 0; j < 8; ++j) {
    float hv = (j < 4 ? fa0[j] : fa1[j - 4]) * inv;
    xv[j] = f2bf(hv * wt[c0 + j]);
  }
  *(u16x8*)&x[base] = xv;
  if (mask[row]) {
    u16x8 av;
#pragma unroll
    for (int j = 0; j < 8; ++j) {
      float hv = (j < 4 ? fa0[j] : fa1[j - 4]) * inv;
      av[j] = f2bf(hv * wa[c0 + j]);
    }
    *(u16x8*)&xc[(size_t)cpos[row] * 2048 + c0] = av;
  }
}

// fused: h += (text? sum4 proj partials : sum16 audio-proj partials via cpos) ;
//        then next input-norm (select) -> x, or final ln_f -> outf
__global__ __launch_bounds__(256) void k_redrms_ffn(
    float* __restrict__ h, const u16* __restrict__ Psk, const u16* __restrict__ Pap,
    const float* __restrict__ wt, const float* __restrict__ wa,
    const float* __restrict__ wf, const int* __restrict__ mask,
    const int* __restrict__ cpos, u16* __restrict__ x, float* __restrict__ outf, int fin) {
  const int row = blockIdx.x, tid = threadIdx.x;
  const int c0 = tid * 8;
  const size_t base = (size_t)row * 2048 + c0;
  float4 a0 = *(const float4*)&h[base];
  float4 a1 = *(const float4*)&h[base + 4];
  float* fa0 = (float*)&a0;
  float* fa1 = (float*)&a1;
  if (mask[row] == 0) {
#pragma unroll
    for (int k = 0; k < 4; ++k) {
      u16x8 pv = *(const u16x8*)&Psk[(size_t)k * 2048 * 2048 + base];
#pragma unroll
      for (int j = 0; j < 4; ++j) fa0[j] += bf2f(pv[j]);
#pragma unroll
      for (int j = 0; j < 4; ++j) fa1[j] += bf2f(pv[4 + j]);
    }
  } else {
    const size_t cb = (size_t)cpos[row] * 2048 + c0;
#pragma unroll
    for (int k = 0; k < 16; ++k) {
      u16x8 pv = *(const u16x8*)&Pap[(size_t)k * 256 * 2048 + cb];
#pragma unroll
      for (int j = 0; j < 4; ++j) fa0[j] += bf2f(pv[j]);
#pragma unroll
      for (int j = 0; j < 4; ++j) fa1[j] += bf2f(pv[4 + j]);
    }
  }
  if (!fin) {
    *(float4*)&h[base] = a0;
    *(float4*)&h[base + 4] = a1;
  }
  float ss = 0.f;
#pragma unroll
  for (int j = 0; j < 4; ++j) ss += fa0[j] * fa0[j] + fa1[j] * fa1[j];
  __shared__ float red[4];
  ss = block_sum256(ss, red);
  const float inv = rsqrtf(ss * (1.0f / 2048.0f) + 1e-5f);
  if (fin) {
    float4 o0, o1;
    float* p0 = (float*)&o0;
    float* p1 = (float*)&o1;
#pragma unroll
    for (int j = 0; j < 4; ++j) {
      p0[j] = fa0[j] * inv * wf[c0 + j];
      p1[j] = fa1[j] * inv * wf[c0 + 4 + j];
    }
    *(float4*)&outf[base] = o0;
    *(float4*)&outf[base + 4] = o1;
  } else {
    const float* w = mask[row] ? wa : wt;
    u16x8 xv;
#pragma unroll
    for (int j = 0; j < 8; ++j) {
      float hv = (j < 4 ? fa0[j] : fa1[j - 4]) * inv;
      xv[j] = f2bf(hv * w[c0 + j]);
    }
    *(u16x8*)&x[base] = xv;
  }
}

// ------------------------------------------------------------- host launch
extern "C" void kernel_launch(void* const* d_in, const int* in_sizes, int n_in,
                              void* d_out, int out_size, void* d_ws, size_t ws_size,
                              hipStream_t stream) {
  const int* ids = (const int*)d_in[0];
  const float* vocab = (const float*)d_in[1];
  const float* audio = (const float*)d_in[2];
  const float* ln_in = (const float*)d_in[3];
  const float* ln_audio_in = (const float*)d_in[4];
  const float* ln_post = (const float*)d_in[5];
  const float* ln_audio_post = (const float*)d_in[6];
  const float* w_qkv = (const float*)d_in[7];
  const float* w_o = (const float*)d_in[8];
  const float* w_fc = (const float*)d_in[9];
  const float* w_proj = (const float*)d_in[10];
  const float* w_afc = (const float*)d_in[11];
  const float* w_aproj = (const float*)d_in[12];
  const float* ln_f = (const float*)d_in[13];
  float* out = (float*)d_out;

  char* p = (char*)d_ws;
  auto alloc = [&](size_t bytes) {
    char* r = p;
    p += (bytes + 255) & ~(size_t)255;
    return r;
  };
  float* h   = (float*)alloc((size_t)2048 * 2048 * 4);
  u16* x     = (u16*)alloc((size_t)2048 * 2048 * 2);
  u16* xc    = (u16*)alloc((size_t)2048 * 2048 * 2);
  u16* o     = (u16*)alloc((size_t)2048 * 2048 * 2);
  int* mask  = (int*)alloc((size_t)2048 * 4);
  int* cpos  = (int*)alloc((size_t)2048 * 4);
  int* cidx  = (int*)alloc((size_t)2048 * 4);
  int* cnt   = (int*)alloc((size_t)64 * 4);
  u16* WtAll = (u16*)alloc((size_t)2 * 46137344 * 2);        // 184 MB: text-path transposed weights
  u16* Q     = (u16*)alloc((size_t)2 * 16 * 1024 * 128 * 2);
  u16* Kb    = (u16*)alloc((size_t)2 * 8 * 1024 * 128 * 2);
  u16* VT    = (u16*)alloc((size_t)2 * 8 * 1024 * 128 * 2);
  char* A    = alloc((size_t)128 * 1024 * 1024);             // 128 MB multi-use region
  char* Bg   = alloc((size_t)24 * 1024 * 1024);              // 24 MB region
  u16* t1    = (u16*)alloc((size_t)2048 * 8192 * 2);
  u16* t1a   = (u16*)alloc((size_t)256 * 8192 * 2);          // audio fc output (4 MB)
  // Region aliases (lifetimes disjoint in stream order), all bf16 partials:
  u16* Pq    = (u16*)A;                          // [2][2048][4096] qkv partials (33.5 MB)
  u16* Psk   = (u16*)A;                          // [4][2048][2048] o/proj partials (33.5 MB)
  u16* Pafc  = (u16*)(A + (size_t)67108864);     // [8][256][8192] audio-fc partials (33.5 MB)
  u16* Paprj = (u16*)Bg;                         // [16][256][2048] audio-proj partials (16.8 MB)
  (void)ws_size; (void)in_sizes; (void)n_in; (void)out_size;

  // merged: text-path weight transposes + embedding/mask/layer-0 norm
  k_trans_embed<<<24576, 256, 0, stream>>>(w_qkv, w_o, w_fc, w_proj, WtAll,
                                           ids, vocab, audio, ln_in, ln_audio_in, h, mask, x);
  k_scan<<<1, 256, 0, stream>>>(mask, cpos, cidx, cnt);

  for (int l = 0; l < 2; ++l) {
    u16* WtL = WtAll + (size_t)l * 46137344;
    u16* Wqkv_t  = WtL;
    u16* Wo_t    = WtL + 8388608;
    u16* Wfc_t   = WtL + 12582912;
    u16* Wproj_t = WtL + 29360128;

    // qkv: 8-phase split-K x2 -> bf16 partials -> scatter reduce
    k_gemm8_qkv<<<256, 512, 0, stream>>>(x, Wqkv_t, Pq);
    k_red_qkv<<<dim3(4, 2048), 256, 0, stream>>>(Pq, Q, Kb, VT);
    // fused flash attention (QBLK=64, full machine)
    k_fattn<<<dim3(16, 32), 256, 0, stream>>>(Q, Kb, VT, o);
    // o-proj split-K x4 -> fused reduce + residual + post-norm
    k_gemm8_sk<<<256, 512, 0, stream>>>(o, 2048, Wo_t, 2048, 8, 512, Psk);
    k_redrms_post<<<2048, 256, 0, stream>>>(h, Psk, ln_post + l * 2048,
                                            ln_audio_post + l * 2048, mask, x, xc, cpos);
    // MERGED text fc + audio fc
    k_fc_afc<<<1280, 512, 0, stream>>>(x, Wfc_t, t1, xc,
                                       w_afc + (size_t)l * 2048 * 8192, Pafc, cnt);
    k_red8_silu<<<dim3(8, 256), 256, 0, stream>>>(Pafc, t1a, cnt);
    // MERGED text proj (split-K x4) + audio proj
    k_sk_aproj<<<768, 512, 0, stream>>>(t1, Wproj_t, Psk, t1a,
                                        w_aproj + (size_t)l * 8192 * 2048, Paprj, cnt);
    // fused: both-path residual add + (next input-norm | final ln_f)
    if (l == 0)
      k_redrms_ffn<<<2048, 256, 0, stream>>>(h, Psk, Paprj, ln_in + 2048,
                                             ln_audio_in + 2048, nullptr, mask, cpos, x,
                                             nullptr, 0);
    else
      k_redrms_ffn<<<2048, 256, 0, stream>>>(h, Psk, Paprj, nullptr, nullptr, ln_f, mask,
                                             cpos, nullptr, out, 1);
  }
}